// Round 16
// baseline (342.050 us; speedup 1.0000x reference)
//
#include <hip/hip_runtime.h>
#include <hip/hip_fp16.h>
#include <math.h>

// 2-layer GCN, fp32: out = sigmoid(gcn(relu(gcn(x, W0, b0)), W1, b1))
// edge_index arrives int32. agg(x@W)==agg(x)@W -> aggregate raw x first.
// Round-16: the 5-kernel CSR build (hist/scanA/scanB/scatter/sort) collapsed
// into ONE grid-resident kernel (256 blocks x 1024 thr, <=1 blk/CU, all
// co-resident) with a device-scope generation grid-barrier (__hip_atomic_*
// AGENT scope for cross-XCD visibility). Kills 4 launch+drain boundaries.
// Pulls/GEMMs unchanged (pulls proven at the random-gather floor).

#define FIN 64
#define FHID 128
#define FOUT 64
#define NPB 128          // nodes per bucket
#define LOGNPB 7
#define BMAX 800         // >= ceil(100000/128)=782
#define G 256            // kbuild blocks (one per CU)
#define TPB 1024
#define CAP 4096         // LDS sort staging

typedef _Float16 f16x2 __attribute__((ext_vector_type(2)));

#if defined(__has_builtin)
#if __has_builtin(__builtin_amdgcn_fdot2)
#define HAS_FDOT2 1
#endif
#endif

__device__ __forceinline__ float dot2(f16x2 a, f16x2 b, float c) {
#ifdef HAS_FDOT2
    return __builtin_amdgcn_fdot2(a, b, c, false);
#else
    c = fmaf((float)a[0], (float)b[0], c);
    return fmaf((float)a[1], (float)b[1], c);
#endif
}

// device-scope generation barrier: all G blocks co-resident by construction.
// Release on arrival RMW publishes prior global stores; acquire on spin/load
// invalidates stale lines (cross-XCD safe per HIP agent-scope semantics).
__device__ __forceinline__ void gridbar(int* cnt, int* gen, int nb) {
    __syncthreads();
    if (threadIdx.x == 0) {
        int g = __hip_atomic_load(gen, __ATOMIC_ACQUIRE, __HIP_MEMORY_SCOPE_AGENT);
        int prev = __hip_atomic_fetch_add(cnt, 1, __ATOMIC_ACQ_REL,
                                          __HIP_MEMORY_SCOPE_AGENT);
        if (prev == nb - 1) {
            __hip_atomic_store(cnt, 0, __ATOMIC_RELAXED, __HIP_MEMORY_SCOPE_AGENT);
            __hip_atomic_fetch_add(gen, 1, __ATOMIC_ACQ_REL,
                                   __HIP_MEMORY_SCOPE_AGENT);
        } else {
            while (__hip_atomic_load(gen, __ATOMIC_ACQUIRE,
                                     __HIP_MEMORY_SCOPE_AGENT) == g)
                __builtin_amdgcn_s_sleep(1);
        }
    }
    __syncthreads();
}

// ---------------- fused CSR build (one grid-resident kernel) ----------------
__global__ __launch_bounds__(TPB, 1) void kbuild(
        const int* __restrict__ src, const int* __restrict__ dst,
        const float* __restrict__ x,
        int* __restrict__ ghist, int* __restrict__ gbase,
        int* __restrict__ tot, int* __restrict__ bb,
        unsigned* __restrict__ pk, int* __restrict__ ssrc,
        int* __restrict__ rp, float* __restrict__ dis,
        __half* __restrict__ yh, int* bar,
        int n, int e, int B, int chunk) {
    __shared__ int h[BMAX];                  // hist, then scatter cursors
    __shared__ int cnt[NPB], pre[NPB];
    __shared__ float disl[NPB];
    __shared__ unsigned stage[CAP];          // 16 KB
    __shared__ int sscan[TPB];

    int g = blockIdx.x, t = threadIdx.x;
    int lo = g * chunk, hi = min(e, lo + chunk);

    // ---- phase A: per-block bucket histogram ----
    for (int i = t; i < B; i += TPB) h[i] = 0;
    __syncthreads();
    for (int i = lo + t; i < hi; i += TPB)
        atomicAdd(&h[dst[i] >> LOGNPB], 1);
    __syncthreads();
    for (int i = t; i < B; i += TPB) ghist[i * G + g] = h[i];

    gridbar(bar, bar + 1, G);

    // ---- phase B1: per-bucket exclusive scan over blocks (1 wave/bucket) ----
    {
        int wid = g * (TPB / 64) + (t >> 6);
        int lane = t & 63;
        if (wid < B) {
            int base = wid * G + lane * 4;   // G==256: 4 values per lane
            int v0 = ghist[base + 0], v1 = ghist[base + 1];
            int v2 = ghist[base + 2], v3 = ghist[base + 3];
            int s4 = v0 + v1 + v2 + v3;
            int sc = s4;
            #pragma unroll
            for (int off = 1; off < 64; off <<= 1) {
                int u = __shfl_up(sc, off);
                if (lane >= off) sc += u;
            }
            int run = sc - s4;               // exclusive prefix
            gbase[base + 0] = run; run += v0;
            gbase[base + 1] = run; run += v1;
            gbase[base + 2] = run; run += v2;
            gbase[base + 3] = run;
            if (lane == 63) tot[wid] = sc;
        }
    }

    gridbar(bar, bar + 1, G);

    // ---- phase B2: block 0 scans tot -> bb ----
    if (g == 0) {
        int v = (t < B) ? tot[t] : 0;
        sscan[t] = v;
        __syncthreads();
        for (int off = 1; off < TPB; off <<= 1) {
            int u = (t >= off) ? sscan[t - off] : 0;
            __syncthreads();
            sscan[t] += u;
            __syncthreads();
        }
        if (t < B) bb[t] = sscan[t] - v;
        if (t == 0) bb[B] = e;
    }

    gridbar(bar, bar + 1, G);

    // ---- phase C: scatter edges into bucket-grouped pk ----
    for (int b = t; b < B; b += TPB) h[b] = bb[b] + gbase[b * G + g];
    __syncthreads();
    for (int i = lo + t; i < hi; i += TPB) {
        int d = dst[i], s = src[i], b = d >> LOGNPB;
        int p = atomicAdd(&h[b], 1);
        pk[p] = ((unsigned)(d & (NPB - 1)) << 17) | (unsigned)s;
    }

    gridbar(bar, bar + 1, G);

    // ---- phase D: bucket-local counting sort + rp/dis + fp16 table ----
    for (int b = g; b < B; b += G) {
        __syncthreads();                     // cnt/stage reuse across buckets
        int blo = bb[b], bhi = bb[b + 1], m = bhi - blo;
        if (t < NPB) cnt[t] = 0;
        __syncthreads();
        for (int i = blo + t; i < bhi; i += TPB)
            atomicAdd(&cnt[pk[i] >> 17], 1);
        __syncthreads();
        if (t < NPB) pre[t] = cnt[t];
        __syncthreads();
        #pragma unroll
        for (int off = 1; off < NPB; off <<= 1) {
            int v = (t < NPB && t >= off) ? pre[t - off] : 0;
            __syncthreads();
            if (t < NPB) pre[t] += v;
            __syncthreads();
        }
        if (t < NPB) {
            int node = b * NPB + t;
            int c = cnt[t];
            int bs = blo + pre[t] - c;       // node segment global start
            float dv = rsqrtf(1.0f + (float)c);
            disl[t] = dv;
            if (node < n) {
                rp[node] = bs;
                dis[node] = dv;
            }
            cnt[t] = bs - blo;               // local cursor
        }
        if (b == 0 && t == 0) rp[n] = e;
        __syncthreads();
        if (m <= CAP) {                      // LDS-staged, coalesced write-out
            for (int i = blo + t; i < bhi; i += TPB) {
                unsigned v = pk[i];
                int p = atomicAdd(&cnt[v >> 17], 1);
                stage[p] = v & 0x1FFFF;
            }
            __syncthreads();
            for (int i = t; i < m; i += TPB) ssrc[blo + i] = (int)stage[i];
        } else {                             // fallback: direct scatter
            for (int i = blo + t; i < bhi; i += TPB) {
                unsigned v = pk[i];
                int p = atomicAdd(&cnt[v >> 17], 1);
                ssrc[blo + p] = (int)(v & 0x1FFFF);
            }
        }
        // fused fp16 table: yh[node][f] = fp16(dis*x); bucket = 2048 float4
        for (int i = t; i < NPB * 16; i += TPB) {
            int node = b * NPB + (i >> 4);
            if (node < n) {
                float d = disl[i >> 4];
                int gi = b * (NPB * 16) + i;
                float4 v = reinterpret_cast<const float4*>(x)[gi];
                __half2 h0, h1;
                h0.x = __float2half(d * v.x); h0.y = __float2half(d * v.y);
                h1.x = __float2half(d * v.z); h1.y = __float2half(d * v.w);
                reinterpret_cast<__half2*>(yh)[gi * 2 + 0] = h0;
                reinterpret_cast<__half2*>(yh)[gi * 2 + 1] = h1;
            }
        }
    }
}

// ---------------- fp16 pull aggregation (8-deep ILP) ----------------
__global__ __launch_bounds__(256) void k_pull16(
        const int* __restrict__ rp, const int* __restrict__ ssrc,
        const float* __restrict__ dis, const __half* __restrict__ yh,
        const float* __restrict__ b1, float* __restrict__ outp,
        __half* __restrict__ outph, int n, int sig) {
    int node4 = blockIdx.x * 4 + (threadIdx.x >> 6);
    if (node4 >= n) return;
    int node = __builtin_amdgcn_readfirstlane(node4);
    int f = threadIdx.x & 63;
    float a0 = __half2float(yh[(size_t)node * 64 + f]);   // self-loop term
    float a1 = 0.f, a2 = 0.f, a3 = 0.f, a4 = 0.f, a5 = 0.f, a6 = 0.f, a7 = 0.f;
    int j = rp[node], end = rp[node + 1];
    for (; j + 7 < end; j += 8) {
        int s0 = ssrc[j],     s1 = ssrc[j + 1], s2 = ssrc[j + 2], s3 = ssrc[j + 3];
        int s4 = ssrc[j + 4], s5 = ssrc[j + 5], s6 = ssrc[j + 6], s7 = ssrc[j + 7];
        a0 += __half2float(yh[(size_t)s0 * 64 + f]);
        a1 += __half2float(yh[(size_t)s1 * 64 + f]);
        a2 += __half2float(yh[(size_t)s2 * 64 + f]);
        a3 += __half2float(yh[(size_t)s3 * 64 + f]);
        a4 += __half2float(yh[(size_t)s4 * 64 + f]);
        a5 += __half2float(yh[(size_t)s5 * 64 + f]);
        a6 += __half2float(yh[(size_t)s6 * 64 + f]);
        a7 += __half2float(yh[(size_t)s7 * 64 + f]);
    }
    for (; j + 1 < end; j += 2) {
        int s0 = ssrc[j], s1 = ssrc[j + 1];
        a0 += __half2float(yh[(size_t)s0 * 64 + f]);
        a1 += __half2float(yh[(size_t)s1 * 64 + f]);
    }
    if (j < end)
        a0 += __half2float(yh[(size_t)ssrc[j] * 64 + f]);
    float v = dis[node] * (((a0 + a1) + (a2 + a3)) + ((a4 + a5) + (a6 + a7)));
    if (sig) {
        v += b1[f];
        outp[(size_t)node * 64 + f] = 1.0f / (1.0f + expf(-v));
    } else {
        outph[(size_t)node * 64 + f] = __float2half(v);
    }
}

// ---------------- split fdot2 GEMMs (weights in VGPRs) ----------------
__global__ __launch_bounds__(256) void k_gemm1(
        const __half* __restrict__ in,     // [n][64] fp16
        const float* __restrict__ W0,      // [64][128] fp32
        const float* __restrict__ b0,      // [128]
        __half* __restrict__ h,            // [n][128] fp16
        int n, int nwaves) {
    int gw = blockIdx.x * 4 + (threadIdx.x >> 6);
    int lane = threadIdx.x & 63;

    f16x2 w0a[32], w0b[32];
    #pragma unroll
    for (int i = 0; i < 32; ++i) {
        w0a[i] = (f16x2){(_Float16)W0[(2 * i) * FHID + lane],
                         (_Float16)W0[(2 * i + 1) * FHID + lane]};
        w0b[i] = (f16x2){(_Float16)W0[(2 * i) * FHID + 64 + lane],
                         (_Float16)W0[(2 * i + 1) * FHID + 64 + lane]};
    }
    float ba = b0[lane], bbias = b0[64 + lane];

    for (int task = gw; task < n; task += nwaves) {
        int row = __builtin_amdgcn_readfirstlane(task);
        const f16x2* srow = reinterpret_cast<const f16x2*>(in + (size_t)row * FIN);
        float aa = ba, ab = bbias;
        #pragma unroll
        for (int i = 0; i < 32; ++i) {
            f16x2 xv = srow[i];
            aa = dot2(xv, w0a[i], aa);
            ab = dot2(xv, w0b[i], ab);
        }
        h[(size_t)row * FHID + lane]      = __float2half(fmaxf(aa, 0.0f));
        h[(size_t)row * FHID + 64 + lane] = __float2half(fmaxf(ab, 0.0f));
    }
}

__global__ __launch_bounds__(256) void k_gemm2(
        const __half* __restrict__ h,      // [n][128] fp16
        const float* __restrict__ W1,      // [128][64] fp32
        const float* __restrict__ dis,
        __half* __restrict__ yh,           // [n][64] fp16
        int n, int nwaves) {
    int gw = blockIdx.x * 4 + (threadIdx.x >> 6);
    int lane = threadIdx.x & 63;

    f16x2 w1c[64];
    #pragma unroll
    for (int i = 0; i < 64; ++i)
        w1c[i] = (f16x2){(_Float16)W1[(2 * i) * FOUT + lane],
                         (_Float16)W1[(2 * i + 1) * FOUT + lane]};

    for (int task = gw; task < n; task += nwaves) {
        int row = __builtin_amdgcn_readfirstlane(task);
        const f16x2* hrow = reinterpret_cast<const f16x2*>(h + (size_t)row * FHID);
        float acc = 0.0f;
        #pragma unroll
        for (int i = 0; i < 64; ++i)
            acc = dot2(hrow[i], w1c[i], acc);
        yh[(size_t)row * FOUT + lane] = __float2half(dis[row] * acc);
    }
}

extern "C" void kernel_launch(void* const* d_in, const int* in_sizes, int n_in,
                              void* d_out, int out_size, void* d_ws, size_t ws_size,
                              hipStream_t stream) {
    const float* x   = (const float*)d_in[0];
    const int*   ei  = (const int*)d_in[1];   // int32 [2, E]
    const float* W0  = (const float*)d_in[2];
    const float* b0  = (const float*)d_in[3];
    const float* W1  = (const float*)d_in[4];
    const float* b1  = (const float*)d_in[5];
    float*       out = (float*)d_out;

    const int n = in_sizes[0] / FIN;        // 100000
    const int e = in_sizes[1] / 2;          // 1600000
    const int* src = ei;
    const int* dst = ei + e;
    if (n > (1 << 17)) return;              // 17-bit packing limit

    const int B = (n + NPB - 1) / NPB;      // 782 buckets
    if (B > BMAX) return;
    const int chunk = (e + G - 1) / G;

    // workspace layout (pk/ghist/gbase/tot/bb/bar dead after kbuild; hh overlays)
    float*    dis  = (float*)d_ws;                        // N
    __half*   bufh = (__half*)(dis + n);                  // N*64 fp16
    int*      ssrc = (int*)(bufh + (size_t)n * FIN);      // E
    int*      rp   = ssrc + e;                            // N+1
    __half*   yh   = (__half*)(rp + (n + 1));             // N*64 fp16
    char*     region = (char*)(yh + (size_t)n * FIN);
    __half*   hh   = (__half*)region;                     // N*128 fp16
    unsigned* pk   = (unsigned*)region;                   // E (overlaid w/ hh)
    int*      ghist = (int*)(pk + e);                     // B*G
    int*      gbase = ghist + (size_t)B * G;              // B*G
    int*      tot   = gbase + (size_t)B * G;              // B
    int*      bb    = tot + B;                            // B+1
    int*      bar   = bb + (B + 1);                       // 2 (cnt, gen)
    size_t region_sz = (size_t)n * FHID * sizeof(__half);
    {
        size_t pkchain = (size_t)((char*)(bar + 2) - region);
        if (pkchain > region_sz) region_sz = pkchain;
    }
    size_t need = (size_t)(region - (char*)d_ws) + region_sz;
    if (ws_size < need) return;

    // barrier flags must start at 0 every call (ws is poisoned once to 0xAA)
    hipMemsetAsync(bar, 0, 2 * sizeof(int), stream);

    // fused CSR build: hist + scans + scatter + sort + fp16 table, 1 kernel
    kbuild<<<G, TPB, 0, stream>>>(src, dst, x, ghist, gbase, tot, bb,
                                  pk, ssrc, rp, dis, yh, bar, n, e, B, chunk);

    // layer 1: bufh = fp16( dis[d]*(y1[d] + sum y1[s]) )
    k_pull16<<<(n + 3) / 4, 256, 0, stream>>>(rp, ssrc, dis, yh, b1,
                                              (float*)nullptr, bufh, n, 0);

    // MLP (split fdot2): hh = fp16(relu(bufh@W0+b0)); yh = fp16(dis*(hh@W1))
    const int blocks = 2048, nwaves = blocks * 4;
    k_gemm1<<<blocks, 256, 0, stream>>>(bufh, W0, b0, hh, n, nwaves);
    k_gemm2<<<blocks, 256, 0, stream>>>(hh, W1, dis, yh, n, nwaves);

    // layer 2: out = sigmoid(dis[d]*(y2[d] + sum y2[s]) + b1)
    k_pull16<<<(n + 3) / 4, 256, 0, stream>>>(rp, ssrc, dis, yh, b1,
                                              out, (__half*)nullptr, n, 1);
}

// Round 17
// 235.330 us; speedup vs baseline: 1.4535x; 1.4535x over previous
//
#include <hip/hip_runtime.h>
#include <hip/hip_fp16.h>
#include <math.h>

// 2-layer GCN, fp32: out = sigmoid(gcn(relu(gcn(x, W0, b0)), W1, b1))
// edge_index arrives int32. agg(x@W)==agg(x)@W -> aggregate raw x first.
// FINAL (= round-14 best, 236.5us): bucket partition (LDS hists, no global
// atomics) -> bucket-local counting sort (LDS-staged coalesced write, fused
// x->fp16 table) -> fp16 pull aggregation x2 (8-deep ILP, at the measured
// random-gather floor: 160MB FETCH @3.5TB/s) around split fdot2
// register-weight GEMMs. Round-16's grid-resident fused build reverted
// (lockstep phases serialized: 200us vs 80us for the split chain).

#define FIN 64
#define FHID 128
#define FOUT 64
#define NPB 128          // nodes per bucket
#define LOGNPB 7
#define BMAX 800         // >= ceil(100000/128)=782
#define G 128            // partition blocks
#define CAP 4096         // LDS sort staging

typedef _Float16 f16x2 __attribute__((ext_vector_type(2)));

#if defined(__has_builtin)
#if __has_builtin(__builtin_amdgcn_fdot2)
#define HAS_FDOT2 1
#endif
#endif

__device__ __forceinline__ float dot2(f16x2 a, f16x2 b, float c) {
#ifdef HAS_FDOT2
    return __builtin_amdgcn_fdot2(a, b, c, false);
#else
    c = fmaf((float)a[0], (float)b[0], c);
    return fmaf((float)a[1], (float)b[1], c);
#endif
}

// ---------------- bucket partition (no global atomics) ----------------

__global__ __launch_bounds__(256) void khist(const int* __restrict__ dst,
                                             int* __restrict__ ghist,
                                             int e, int B, int chunk) {
    __shared__ int h[BMAX];
    int g = blockIdx.x, t = threadIdx.x;
    for (int i = t; i < B; i += 256) h[i] = 0;
    __syncthreads();
    int lo = g * chunk, hi = min(e, lo + chunk);
    for (int i = lo + t; i < hi; i += 256)
        atomicAdd(&h[dst[i] >> LOGNPB], 1);
    __syncthreads();
    for (int i = t; i < B; i += 256) ghist[i * G + g] = h[i];
}

__global__ __launch_bounds__(256) void kscanA(const int* __restrict__ ghist,
                                              int* __restrict__ gbase,
                                              int* __restrict__ tot, int B) {
    int per = (B + gridDim.x - 1) / gridDim.x;
    int b0 = blockIdx.x * per, b1 = min(B, b0 + per);
    for (int b = b0 + threadIdx.x; b < b1; b += 256) {
        int run = 0;
        #pragma unroll 8
        for (int g = 0; g < G; ++g) {
            int v = ghist[b * G + g];
            gbase[b * G + g] = run;
            run += v;
        }
        tot[b] = run;
    }
}

__global__ __launch_bounds__(256) void kscanB(const int* __restrict__ tot,
                                              int* __restrict__ bb, int B, int e) {
    __shared__ int s[256];
    __shared__ int chunkoff;
    int t = threadIdx.x;
    if (t == 0) chunkoff = 0;
    __syncthreads();
    for (int c0 = 0; c0 < B; c0 += 256) {
        int v = (c0 + t < B) ? tot[c0 + t] : 0;
        s[t] = v;
        __syncthreads();
        for (int off = 1; off < 256; off <<= 1) {
            int u = (t >= off) ? s[t - off] : 0;
            __syncthreads();
            s[t] += u;
            __syncthreads();
        }
        if (c0 + t < B) bb[c0 + t] = s[t] - v + chunkoff;
        __syncthreads();
        if (t == 255) chunkoff += s[255];
        __syncthreads();
    }
    if (t == 0) bb[B] = e;
}

__global__ __launch_bounds__(256) void kscatter(const int* __restrict__ src,
                                                const int* __restrict__ dst,
                                                const int* __restrict__ gbase,
                                                const int* __restrict__ bb,
                                                unsigned* __restrict__ pk,
                                                int e, int B, int chunk) {
    __shared__ int cur[BMAX];
    int g = blockIdx.x, t = threadIdx.x;
    for (int b = t; b < B; b += 256) cur[b] = bb[b] + gbase[b * G + g];
    __syncthreads();
    int lo = g * chunk, hi = min(e, lo + chunk);
    for (int i = lo + t; i < hi; i += 256) {
        int d = dst[i], s = src[i], b = d >> LOGNPB;
        int p = atomicAdd(&cur[b], 1);
        pk[p] = ((unsigned)(d & (NPB - 1)) << 17) | (unsigned)s;
    }
}

// bucket-local counting sort, key = localdst*4 | srcrange (src>>15);
// rp/dis; coalesced ssrc write; fused x->fp16 scaled-table conversion.
__global__ __launch_bounds__(256) void kpsort(const unsigned* __restrict__ pk,
                                              const int* __restrict__ bb,
                                              const float* __restrict__ x,
                                              int* __restrict__ ssrc,
                                              int* __restrict__ rp,
                                              float* __restrict__ dis,
                                              __half* __restrict__ yh,
                                              int n, int e) {
    __shared__ int cnt[NPB * 4];             // 512 keys
    __shared__ int pre[NPB];
    __shared__ float disl[NPB];
    __shared__ unsigned stage[CAP];          // 16 KB
    int b = blockIdx.x, t = threadIdx.x;
    int lo = bb[b], hi = bb[b + 1], m = hi - lo;
    for (int i = t; i < NPB * 4; i += 256) cnt[i] = 0;
    __syncthreads();
    for (int i = lo + t; i < hi; i += 256) {
        unsigned v = pk[i];
        int key = (int)((v >> 17) << 2) | (int)((v & 0x1FFFF) >> 15);
        atomicAdd(&cnt[key], 1);
    }
    __syncthreads();
    int tot_t = 0;
    if (t < NPB)
        tot_t = cnt[4 * t] + cnt[4 * t + 1] + cnt[4 * t + 2] + cnt[4 * t + 3];
    if (t < NPB) pre[t] = tot_t;
    __syncthreads();
    #pragma unroll
    for (int off = 1; off < NPB; off <<= 1) {
        int v = (t < NPB && t >= off) ? pre[t - off] : 0;
        __syncthreads();
        if (t < NPB) pre[t] += v;
        __syncthreads();
    }
    if (t < NPB) {
        int node = b * NPB + t;
        int c = tot_t;
        int bs = lo + pre[t] - c;
        float dv = rsqrtf(1.0f + (float)c);
        disl[t] = dv;
        if (node < n) {
            rp[node] = bs;
            dis[node] = dv;
        }
        int c0 = cnt[4 * t], c1 = cnt[4 * t + 1], c2 = cnt[4 * t + 2];
        int run = bs - lo;
        cnt[4 * t]     = run;
        cnt[4 * t + 1] = run + c0;
        cnt[4 * t + 2] = run + c0 + c1;
        cnt[4 * t + 3] = run + c0 + c1 + c2;
    }
    if (b == 0 && t == 0) rp[n] = e;
    __syncthreads();
    if (m <= CAP) {
        for (int i = lo + t; i < hi; i += 256) {
            unsigned v = pk[i];
            int key = (int)((v >> 17) << 2) | (int)((v & 0x1FFFF) >> 15);
            int p = atomicAdd(&cnt[key], 1);
            stage[p] = v & 0x1FFFF;
        }
        __syncthreads();
        for (int i = t; i < m; i += 256) ssrc[lo + i] = (int)stage[i];
    } else {
        for (int i = lo + t; i < hi; i += 256) {
            unsigned v = pk[i];
            int key = (int)((v >> 17) << 2) | (int)((v & 0x1FFFF) >> 15);
            int p = atomicAdd(&cnt[key], 1);
            ssrc[lo + p] = (int)(v & 0x1FFFF);
        }
    }
    // yh[node][f] = fp16(dis[node]*x[node][f]); bucket = 2048 float4
    for (int i = t; i < NPB * 16; i += 256) {
        int node = b * NPB + (i >> 4);
        if (node < n) {
            float d = disl[i >> 4];
            int gi = b * (NPB * 16) + i;
            float4 v = reinterpret_cast<const float4*>(x)[gi];
            __half2 h0, h1;
            h0.x = __float2half(d * v.x); h0.y = __float2half(d * v.y);
            h1.x = __float2half(d * v.z); h1.y = __float2half(d * v.w);
            reinterpret_cast<__half2*>(yh)[gi * 2 + 0] = h0;
            reinterpret_cast<__half2*>(yh)[gi * 2 + 1] = h1;
        }
    }
}

// ---------------- fp16 pull aggregation (8-deep ILP) ----------------
__global__ __launch_bounds__(256) void k_pull16(
        const int* __restrict__ rp, const int* __restrict__ ssrc,
        const float* __restrict__ dis, const __half* __restrict__ yh,
        const float* __restrict__ b1, float* __restrict__ outp,
        __half* __restrict__ outph, int n, int sig) {
    int node4 = blockIdx.x * 4 + (threadIdx.x >> 6);
    if (node4 >= n) return;
    int node = __builtin_amdgcn_readfirstlane(node4);
    int f = threadIdx.x & 63;
    float a0 = __half2float(yh[(size_t)node * 64 + f]);   // self-loop term
    float a1 = 0.f, a2 = 0.f, a3 = 0.f, a4 = 0.f, a5 = 0.f, a6 = 0.f, a7 = 0.f;
    int j = rp[node], end = rp[node + 1];
    for (; j + 7 < end; j += 8) {
        int s0 = ssrc[j],     s1 = ssrc[j + 1], s2 = ssrc[j + 2], s3 = ssrc[j + 3];
        int s4 = ssrc[j + 4], s5 = ssrc[j + 5], s6 = ssrc[j + 6], s7 = ssrc[j + 7];
        a0 += __half2float(yh[(size_t)s0 * 64 + f]);
        a1 += __half2float(yh[(size_t)s1 * 64 + f]);
        a2 += __half2float(yh[(size_t)s2 * 64 + f]);
        a3 += __half2float(yh[(size_t)s3 * 64 + f]);
        a4 += __half2float(yh[(size_t)s4 * 64 + f]);
        a5 += __half2float(yh[(size_t)s5 * 64 + f]);
        a6 += __half2float(yh[(size_t)s6 * 64 + f]);
        a7 += __half2float(yh[(size_t)s7 * 64 + f]);
    }
    for (; j + 1 < end; j += 2) {
        int s0 = ssrc[j], s1 = ssrc[j + 1];
        a0 += __half2float(yh[(size_t)s0 * 64 + f]);
        a1 += __half2float(yh[(size_t)s1 * 64 + f]);
    }
    if (j < end)
        a0 += __half2float(yh[(size_t)ssrc[j] * 64 + f]);
    float v = dis[node] * (((a0 + a1) + (a2 + a3)) + ((a4 + a5) + (a6 + a7)));
    if (sig) {
        v += b1[f];
        outp[(size_t)node * 64 + f] = 1.0f / (1.0f + expf(-v));
    } else {
        outph[(size_t)node * 64 + f] = __float2half(v);
    }
}

// ---------------- split fdot2 GEMMs (weights in VGPRs) ----------------
// G1: hh[row][128] = fp16(relu(bufh[row][64] @ W0 + b0)). One wave per row;
// lane owns cols lane and lane+64; W0 columns packed half2 (64 VGPR).
__global__ __launch_bounds__(256) void k_gemm1(
        const __half* __restrict__ in,     // [n][64] fp16
        const float* __restrict__ W0,      // [64][128] fp32
        const float* __restrict__ b0,      // [128]
        __half* __restrict__ h,            // [n][128] fp16
        int n, int nwaves) {
    int gw = blockIdx.x * 4 + (threadIdx.x >> 6);
    int lane = threadIdx.x & 63;

    f16x2 w0a[32], w0b[32];
    #pragma unroll
    for (int i = 0; i < 32; ++i) {
        w0a[i] = (f16x2){(_Float16)W0[(2 * i) * FHID + lane],
                         (_Float16)W0[(2 * i + 1) * FHID + lane]};
        w0b[i] = (f16x2){(_Float16)W0[(2 * i) * FHID + 64 + lane],
                         (_Float16)W0[(2 * i + 1) * FHID + 64 + lane]};
    }
    float ba = b0[lane], bbias = b0[64 + lane];

    for (int task = gw; task < n; task += nwaves) {
        int row = __builtin_amdgcn_readfirstlane(task);
        const f16x2* srow = reinterpret_cast<const f16x2*>(in + (size_t)row * FIN);
        float aa = ba, ab = bbias;
        #pragma unroll
        for (int i = 0; i < 32; ++i) {
            f16x2 xv = srow[i];
            aa = dot2(xv, w0a[i], aa);
            ab = dot2(xv, w0b[i], ab);
        }
        h[(size_t)row * FHID + lane]      = __float2half(fmaxf(aa, 0.0f));
        h[(size_t)row * FHID + 64 + lane] = __float2half(fmaxf(ab, 0.0f));
    }
}

// G2: yh[row][64] = fp16( dis[row] * (hh[row][128] @ W1) ). One wave per row.
__global__ __launch_bounds__(256) void k_gemm2(
        const __half* __restrict__ h,      // [n][128] fp16
        const float* __restrict__ W1,      // [128][64] fp32
        const float* __restrict__ dis,
        __half* __restrict__ yh,           // [n][64] fp16
        int n, int nwaves) {
    int gw = blockIdx.x * 4 + (threadIdx.x >> 6);
    int lane = threadIdx.x & 63;

    f16x2 w1c[64];
    #pragma unroll
    for (int i = 0; i < 64; ++i)
        w1c[i] = (f16x2){(_Float16)W1[(2 * i) * FOUT + lane],
                         (_Float16)W1[(2 * i + 1) * FOUT + lane]};

    for (int task = gw; task < n; task += nwaves) {
        int row = __builtin_amdgcn_readfirstlane(task);
        const f16x2* hrow = reinterpret_cast<const f16x2*>(h + (size_t)row * FHID);
        float acc = 0.0f;
        #pragma unroll
        for (int i = 0; i < 64; ++i)
            acc = dot2(hrow[i], w1c[i], acc);
        yh[(size_t)row * FOUT + lane] = __float2half(dis[row] * acc);
    }
}

extern "C" void kernel_launch(void* const* d_in, const int* in_sizes, int n_in,
                              void* d_out, int out_size, void* d_ws, size_t ws_size,
                              hipStream_t stream) {
    const float* x   = (const float*)d_in[0];
    const int*   ei  = (const int*)d_in[1];   // int32 [2, E]
    const float* W0  = (const float*)d_in[2];
    const float* b0  = (const float*)d_in[3];
    const float* W1  = (const float*)d_in[4];
    const float* b1  = (const float*)d_in[5];
    float*       out = (float*)d_out;

    const int n = in_sizes[0] / FIN;        // 100000
    const int e = in_sizes[1] / 2;          // 1600000
    const int* src = ei;
    const int* dst = ei + e;
    if (n > (1 << 17)) return;              // 17-bit packing / 4-range limit

    const int B = (n + NPB - 1) / NPB;      // 782 buckets
    if (B > BMAX) return;
    const int chunk = (e + G - 1) / G;

    // workspace layout (pk/ghist/gbase/tot/bb dead after kpsort; hh overlays pk)
    float*    dis  = (float*)d_ws;                        // N
    __half*   bufh = (__half*)(dis + n);                  // N*64 fp16
    int*      ssrc = (int*)(bufh + (size_t)n * FIN);      // E
    int*      rp   = ssrc + e;                            // N+1
    __half*   yh   = (__half*)(rp + (n + 1));             // N*64 fp16
    char*     region = (char*)(yh + (size_t)n * FIN);
    __half*   hh   = (__half*)region;                     // N*128 fp16
    unsigned* pk   = (unsigned*)region;                   // E (overlaid w/ hh)
    int*      ghist = (int*)(pk + e);                     // B*G
    int*      gbase = ghist + (size_t)B * G;              // B*G
    int*      tot   = gbase + (size_t)B * G;              // B
    int*      bb    = tot + B;                            // B+1
    size_t region_sz = (size_t)n * FHID * sizeof(__half);
    {
        size_t pkchain = (size_t)((char*)(bb + B + 1) - region);
        if (pkchain > region_sz) region_sz = pkchain;
    }
    size_t need = (size_t)(region - (char*)d_ws) + region_sz;
    if (ws_size < need) return;

    // CSR build: bucket partition + range-segmented counting sort (+fp16 table)
    khist<<<G, 256, 0, stream>>>(dst, ghist, e, B, chunk);
    kscanA<<<8, 256, 0, stream>>>(ghist, gbase, tot, B);
    kscanB<<<1, 256, 0, stream>>>(tot, bb, B, e);
    kscatter<<<G, 256, 0, stream>>>(src, dst, gbase, bb, pk, e, B, chunk);
    kpsort<<<B, 256, 0, stream>>>(pk, bb, x, ssrc, rp, dis, yh, n, e);

    // layer 1: bufh = fp16( dis[d]*(y1[d] + sum y1[s]) )
    k_pull16<<<(n + 3) / 4, 256, 0, stream>>>(rp, ssrc, dis, yh, b1,
                                              (float*)nullptr, bufh, n, 0);

    // MLP (split fdot2): hh = fp16(relu(bufh@W0+b0)); yh = fp16(dis*(hh@W1))
    const int blocks = 2048, nwaves = blocks * 4;
    k_gemm1<<<blocks, 256, 0, stream>>>(bufh, W0, b0, hh, n, nwaves);
    k_gemm2<<<blocks, 256, 0, stream>>>(hh, W1, dis, yh, n, nwaves);

    // layer 2: out = sigmoid(dis[d]*(y2[d] + sum y2[s]) + b1)
    k_pull16<<<(n + 3) / 4, 256, 0, stream>>>(rp, ssrc, dis, yh, b1,
                                              out, (__half*)nullptr, n, 1);
}